// Round 1
// baseline (10546.526 us; speedup 1.0000x reference)
//
#include <hip/hip_runtime.h>

#define TT 256
#define BATCH 2048
#define DATA 32
#define WIDTH 128
#define INSZ 96
#define RPB 8          // rows per block -> 256 blocks
#define WSLOTS 52      // rolling history window (max lookback = 51 steps)

// 128-wide hidden layer: thread computes output column oW for rows rj0, rj0+2, rj0+4, rj0+6.
template<int K, int XSTRIDE, int HSTRIDE>
__device__ __forceinline__ void layer128_relu(
    const float* __restrict__ Wm, const float* __restrict__ bv,
    const float* x, float* h, int oW, int rj0)
{
    float a0 = bv[oW], a1 = a0, a2 = a0, a3 = a0;
    const float* wr = Wm + oW * K;
    #pragma unroll 4
    for (int k = 0; k < K; k += 4) {
        const float4 wv  = *(const float4*)(wr + k);
        const float4 x0v = *(const float4*)(x + (rj0    ) * XSTRIDE + k);
        const float4 x1v = *(const float4*)(x + (rj0 + 2) * XSTRIDE + k);
        const float4 x2v = *(const float4*)(x + (rj0 + 4) * XSTRIDE + k);
        const float4 x3v = *(const float4*)(x + (rj0 + 6) * XSTRIDE + k);
        a0 = fmaf(wv.x, x0v.x, a0); a0 = fmaf(wv.y, x0v.y, a0);
        a0 = fmaf(wv.z, x0v.z, a0); a0 = fmaf(wv.w, x0v.w, a0);
        a1 = fmaf(wv.x, x1v.x, a1); a1 = fmaf(wv.y, x1v.y, a1);
        a1 = fmaf(wv.z, x1v.z, a1); a1 = fmaf(wv.w, x1v.w, a1);
        a2 = fmaf(wv.x, x2v.x, a2); a2 = fmaf(wv.y, x2v.y, a2);
        a2 = fmaf(wv.z, x2v.z, a2); a2 = fmaf(wv.w, x2v.w, a2);
        a3 = fmaf(wv.x, x3v.x, a3); a3 = fmaf(wv.y, x3v.y, a3);
        a3 = fmaf(wv.z, x3v.z, a3); a3 = fmaf(wv.w, x3v.w, a3);
    }
    h[(rj0    ) * HSTRIDE + oW] = fmaxf(a0, 0.0f);
    h[(rj0 + 2) * HSTRIDE + oW] = fmaxf(a1, 0.0f);
    h[(rj0 + 4) * HSTRIDE + oW] = fmaxf(a2, 0.0f);
    h[(rj0 + 6) * HSTRIDE + oW] = fmaxf(a3, 0.0f);
}

__global__ __launch_bounds__(256) void dde_fused(
    const float* __restrict__ ts, const float* __restrict__ y0,
    const float* __restrict__ W0, const float* __restrict__ b0,
    const float* __restrict__ W1, const float* __restrict__ b1,
    const float* __restrict__ W2, const float* __restrict__ b2,
    const float* __restrict__ W3, const float* __restrict__ b3,
    float* __restrict__ out)
{
    __shared__ __align__(16) float hist[WSLOTS][RPB][DATA]; // 53248 B, thread-private columns
    __shared__ __align__(16) float xb[RPB][100];            // 96 + pad, row stride 400B (16B-aligned)
    __shared__ __align__(16) float hA[RPB][132];            // 128 + pad, row stride 528B
    __shared__ __align__(16) float hB[RPB][132];

    const int tid = threadIdx.x;
    const int r   = tid >> 5;      // 0..7   (owner row within block)
    const int d   = tid & 31;      // 0..31  (owner data dim)
    const int row = blockIdx.x * RPB + r;   // global batch row
    const int oW  = tid & 127;     // output column for the 128-wide layers
    const int rj0 = tid >> 7;      // 0/1 -> rows rj0, rj0+2, rj0+4, rj0+6

    // zero history window (each flat index idx has idx%256 == owner tid -> self-consistent)
    for (int idx = tid; idx < WSLOTS * RPB * DATA; idx += 256)
        ((float*)hist)[idx] = 0.0f;

    if (blockIdx.x == 0 && tid == 0)
        out[(size_t)TT * BATCH * DATA] = 255.0f;   // second tuple output: int32(T-1)

    const float t0  = ts[0];
    const float dt0 = ts[1] - ts[0];

    float y = y0[row * DATA + d];
    hist[0][r][d] = y;
    out[row * DATA + d] = y;       // ys[0] = y0
    __syncthreads();

    float k1 = 0.0f, k2 = 0.0f, k3 = 0.0f;

    for (int i = 0; i < TT - 1; ++i) {
        const float t  = ts[i];
        const float dt = ts[i + 1] - t;

        for (int st = 0; st < 3; ++st) {
            // ---- assemble x = [y_stage, lookup(t_q-1), lookup(t_q-2)] (thread-private reads) ----
            const float toff = (st == 0) ? 0.0f : ((st == 1) ? 0.5f : 0.75f);
            const float tq = fmaf(toff, dt, t);
            float yst;
            if      (st == 0) yst = y;
            else if (st == 1) yst = fmaf(0.5f * dt, k1, y);
            else              yst = fmaf(0.75f * dt, k2, y);
            xb[r][d] = yst;
            #pragma unroll
            for (int dl = 0; dl < 2; ++dl) {
                const float tau = (dl == 0) ? 1.0f : 2.0f;
                float s = (tq - tau - t0) / dt0;
                s = fminf(fmaxf(s, 0.0f), 255.0f);
                const int   i0 = (int)s;               // s>=0: trunc == floor
                const int   i1 = min(i0 + 1, TT - 1);
                const float w  = s - (float)i0;
                const float v  = (1.0f - w) * hist[i0 % WSLOTS][r][d]
                               +         w  * hist[i1 % WSLOTS][r][d];
                xb[r][DATA + dl * DATA + d] = v;
            }
            __syncthreads();

            // ---- MLP ----
            layer128_relu<INSZ, 100, 132>(W0, b0, &xb[0][0], &hA[0][0], oW, rj0);
            __syncthreads();
            layer128_relu<WIDTH, 132, 132>(W1, b1, &hA[0][0], &hB[0][0], oW, rj0);
            __syncthreads();
            layer128_relu<WIDTH, 132, 132>(W2, b2, &hB[0][0], &hA[0][0], oW, rj0);
            __syncthreads();

            // L3: 32 outputs -> item (r,d) owned by this thread; k stays in a register
            {
                float a = b3[d];
                const float* wr = W3 + d * WIDTH;
                const float* xr = &hA[r][0];
                #pragma unroll 4
                for (int k = 0; k < WIDTH; k += 4) {
                    const float4 wv = *(const float4*)(wr + k);
                    const float4 xv = *(const float4*)(xr + k);
                    a = fmaf(wv.x, xv.x, a); a = fmaf(wv.y, xv.y, a);
                    a = fmaf(wv.z, xv.z, a); a = fmaf(wv.w, xv.w, a);
                }
                if      (st == 0) k1 = a;
                else if (st == 1) k2 = a;
                else              k3 = a;
            }
            // next iteration's xb write is fenced by the post-assembly barrier; hist is thread-private
        }

        const float ksum = (2.0f / 9.0f) * k1 + (1.0f / 3.0f) * k2 + (4.0f / 9.0f) * k3;
        y = fmaf(dt, ksum, y);

        hist[(i + 1) % WSLOTS][r][d] = y;                       // thread-private slot
        out[(size_t)(i + 1) * BATCH * DATA + row * DATA + d] = y;
    }
}

extern "C" void kernel_launch(void* const* d_in, const int* in_sizes, int n_in,
                              void* d_out, int out_size, void* d_ws, size_t ws_size,
                              hipStream_t stream) {
    const float* ts = (const float*)d_in[0];
    const float* y0 = (const float*)d_in[1];
    const float* W0 = (const float*)d_in[2];
    const float* b0 = (const float*)d_in[3];
    const float* W1 = (const float*)d_in[4];
    const float* b1 = (const float*)d_in[5];
    const float* W2 = (const float*)d_in[6];
    const float* b2 = (const float*)d_in[7];
    const float* W3 = (const float*)d_in[8];
    const float* b3 = (const float*)d_in[9];

    dde_fused<<<dim3(BATCH / RPB), dim3(256), 0, stream>>>(
        ts, y0, W0, b0, W1, b1, W2, b2, W3, b3, (float*)d_out);
}

// Round 2
// 1195.567 us; speedup vs baseline: 8.8214x; 8.8214x over previous
//
#include <hip/hip_runtime.h>

#define TT 256
#define BATCH 2048
#define DATA 32
#define RPB 8          // batch rows per block -> 256 blocks
#define WSLOTS 52      // rolling history window (max lookback = 51 steps)
#define NT 512         // 8 waves per block

typedef __bf16 bf16x8 __attribute__((ext_vector_type(8)));
typedef float f32x4 __attribute__((ext_vector_type(4)));

__device__ __forceinline__ unsigned short f2bf(float f) {
    union { float f; unsigned u; } v; v.f = f;
    return (unsigned short)((v.u + 0x7FFFu + ((v.u >> 16) & 1u)) >> 16);  // RN
}
__device__ __forceinline__ float bf2f(unsigned short h) {
    union { unsigned u; float f; } v; v.u = ((unsigned)h) << 16;
    return v.f;
}

// Swizzled bf16 row-major tile: row stride 256B, 16B slot index XORed with (row&7).
// Same swizzle on write and read -> contents consistent, banks spread (G4).
__device__ __forceinline__ bf16x8 ldfrag(const char* base, int row, int kbyte) {
    return *(const bf16x8*)(base + row * 256 + (kbyte ^ ((row & 7) << 4)));
}

// One 16-col output tile of X[16 x K] @ W^T: A row = lane&15 (batch row),
// B row in W = cbase + (lane&15) (output col), k-bytes = kc*64 + (lane>>4)*16.
__device__ __forceinline__ f32x4 tile_mm(const char* xbuf, const char* wmat,
                                         int cbase, int kchunks, int lane) {
    f32x4 acc = {0.f, 0.f, 0.f, 0.f};
    const int arow = lane & 15;
    const int brow = cbase + (lane & 15);
    const int koff = (lane >> 4) << 4;
    #pragma unroll
    for (int kc = 0; kc < 4; ++kc) {
        if (kc < kchunks) {
            bf16x8 a = ldfrag(xbuf, arow, kc * 64 + koff);
            bf16x8 b = ldfrag(wmat, brow, kc * 64 + koff);
            acc = __builtin_amdgcn_mfma_f32_16x16x32_bf16(a, b, acc, 0, 0, 0);
        }
    }
    return acc;
}

// D layout: col = lane&15, row = (lane>>4)*4 + j. Only rows 0..7 (M=8) are real.
__device__ __forceinline__ void store_tile_relu(char* hdst, const f32x4& acc,
                                                int cbase, int lane, const float* bias) {
    const int g = lane >> 4;
    if (g < 2) {
        const int col = cbase + (lane & 15);
        const float bv = bias[col];
        #pragma unroll
        for (int j = 0; j < 4; ++j) {
            const int m = g * 4 + j;
            const float h = fmaxf(acc[j] + bv, 0.0f);
            *(unsigned short*)(hdst + m * 256 + ((col * 2) ^ ((m & 7) << 4))) = f2bf(h);
        }
    }
}

// fp32 [rows x K] global -> swizzled bf16 LDS rows (256B stride)
__device__ __forceinline__ void stage_w(const float* __restrict__ src, char* dst,
                                        int rows, int K, int tid) {
    const int gk = K >> 3;
    const int groups = rows * gk;
    for (int g = tid; g < groups; g += NT) {
        const int o = g / gk;
        const int k8 = g - o * gk;
        const float* s = src + o * K + k8 * 8;
        __align__(16) unsigned short tmp[8];
        #pragma unroll
        for (int j = 0; j < 8; ++j) tmp[j] = f2bf(s[j]);
        *(uint4*)(dst + o * 256 + ((k8 * 16) ^ ((o & 7) << 4))) = *(const uint4*)tmp;
    }
}

__global__ __launch_bounds__(NT) void dde_mfma(
    const float* __restrict__ ts, const float* __restrict__ y0,
    const float* __restrict__ W0, const float* __restrict__ b0,
    const float* __restrict__ W1, const float* __restrict__ b1,
    const float* __restrict__ W2, const float* __restrict__ b2,
    const float* __restrict__ W3, const float* __restrict__ b3,
    float* __restrict__ out)
{
    __shared__ __align__(16) unsigned short histB[WSLOTS][RPB][DATA]; // 26624 B, bf16
    __shared__ __align__(16) char W0s[128 * 256];   // 32 KB (96 cols used, padded)
    __shared__ __align__(16) char W1s[128 * 256];   // 32 KB
    __shared__ __align__(16) char W2s[128 * 256];   // 32 KB
    __shared__ __align__(16) char W3s[32 * 256];    // 8 KB
    __shared__ __align__(16) char xB[16 * 256];     // x rows 0..7 live, 8..15 zero
    __shared__ __align__(16) char hA[16 * 256];
    __shared__ __align__(16) char hB[16 * 256];
    __shared__ float kb[3][RPB][DATA];              // k1,k2,k3 fp32
    __shared__ float biasb[3 * 128 + 32];
    __shared__ float tsb[TT];
    // total ~151 KB LDS -> 1 block/CU

    const int tid  = threadIdx.x;
    const int lane = tid & 63;
    const int wv   = tid >> 6;          // wave 0..7 -> output-col tile
    const int r    = tid >> 5;          // (valid for tid<256)
    const int d    = tid & 31;
    const int row  = blockIdx.x * RPB + (r & 7);

    // ---- init: zero LDS buffers that are read-before-full-write ----
    for (int idx = tid; idx < (int)(sizeof(histB) / 4); idx += NT) ((unsigned*)histB)[idx] = 0u;
    for (int idx = tid; idx < 1024; idx += NT) {
        ((unsigned*)xB)[idx] = 0u;
        ((unsigned*)hA)[idx] = 0u;
        ((unsigned*)hB)[idx] = 0u;
    }
    // ---- stage weights (bf16, swizzled) + biases + ts ----
    stage_w(W0, W0s, 128, 96, tid);
    stage_w(W1, W1s, 128, 128, tid);
    stage_w(W2, W2s, 128, 128, tid);
    stage_w(W3, W3s, 32, 128, tid);
    for (int i2 = tid; i2 < 3 * 128 + 32; i2 += NT) {
        float v;
        if      (i2 < 128) v = b0[i2];
        else if (i2 < 256) v = b1[i2 - 128];
        else if (i2 < 384) v = b2[i2 - 256];
        else               v = b3[i2 - 384];
        biasb[i2] = v;
    }
    if (tid < TT) tsb[tid] = ts[tid];

    float y = 0.0f;
    if (tid < 256) {
        y = y0[row * DATA + d];
        histB[0][r][d] = f2bf(y);
        out[row * DATA + d] = y;                    // ys[0] = y0 (exact fp32)
    }
    if (blockIdx.x == 0 && tid == 0)
        out[(size_t)TT * BATCH * DATA] = 255.0f;    // second tuple output int32(T-1)
    __syncthreads();

    const float t0v  = tsb[0];
    const float dt0  = tsb[1] - tsb[0];
    const float ivd0 = 1.0f / dt0;

    for (int i = 0; i < TT - 1; ++i) {
        const float t  = tsb[i];
        const float dt = tsb[i + 1] - t;

        for (int st = 0; st < 3; ++st) {
            // ---- assemble x = [y_stage | lookup(tq-1) | lookup(tq-2)] as bf16 ----
            if (tid < 256) {
                float yst;
                if      (st == 0) yst = y;
                else if (st == 1) yst = fmaf(0.5f * dt, kb[0][r][d], y);
                else              yst = fmaf(0.75f * dt, kb[1][r][d], y);
                const float toff = (st == 0) ? 0.0f : ((st == 1) ? 0.5f : 0.75f);
                const float tq   = fmaf(toff, dt, t);
                *(unsigned short*)(xB + r * 256 + ((d * 2) ^ ((r & 7) << 4))) = f2bf(yst);
                #pragma unroll
                for (int dl = 0; dl < 2; ++dl) {
                    const float tau = dl ? 2.0f : 1.0f;
                    float s = (tq - tau - t0v) * ivd0;
                    s = fminf(fmaxf(s, 0.0f), 255.0f);
                    const int   i0 = (int)s;
                    const int   i1 = (i0 + 1 < TT - 1) ? i0 + 1 : TT - 1;
                    const float wg = s - (float)i0;
                    const float v0 = bf2f(histB[i0 % WSLOTS][r][d]);
                    const float v1 = bf2f(histB[i1 % WSLOTS][r][d]);
                    const int   c  = 32 + dl * 32 + d;
                    *(unsigned short*)(xB + r * 256 + ((c * 2) ^ ((r & 7) << 4))) =
                        f2bf(fmaf(wg, v1 - v0, v0));
                }
            }
            __syncthreads();                                        // (1)
            { f32x4 a = tile_mm(xB, W0s, wv * 16, 3, lane);
              store_tile_relu(hA, a, wv * 16, lane, biasb); }
            __syncthreads();                                        // (2)
            { f32x4 a = tile_mm(hA, W1s, wv * 16, 4, lane);
              store_tile_relu(hB, a, wv * 16, lane, biasb + 128); }
            __syncthreads();                                        // (3)
            { f32x4 a = tile_mm(hB, W2s, wv * 16, 4, lane);
              store_tile_relu(hA, a, wv * 16, lane, biasb + 256); }
            __syncthreads();                                        // (4)
            if (wv < 2) {                                           // L3: N=32
                f32x4 a = tile_mm(hA, W3s, wv * 16, 4, lane);
                const int g = lane >> 4;
                if (g < 2) {
                    const int col = wv * 16 + (lane & 15);
                    const float bv = biasb[384 + col];
                    #pragma unroll
                    for (int j = 0; j < 4; ++j)
                        kb[st][g * 4 + j][col] = a[j] + bv;         // fp32, no relu
                }
            }
            __syncthreads();                                        // (5)
        }

        if (tid < 256) {
            const float k1v = kb[0][r][d], k2v = kb[1][r][d], k3v = kb[2][r][d];
            const float ks  = (2.0f / 9.0f) * k1v + (1.0f / 3.0f) * k2v + (4.0f / 9.0f) * k3v;
            y = fmaf(dt, ks, y);
            histB[(i + 1) % WSLOTS][r][d] = f2bf(y);                // owner-thread slot
            out[(size_t)(i + 1) * BATCH * DATA + row * DATA + d] = y;  // coalesced 1KB/block
        }
        // next stage-0 assembly only writes thread-owned xB slots; xB's last readers
        // (stage-2 L0) are 4 barriers back -> no extra barrier needed here.
    }
}

extern "C" void kernel_launch(void* const* d_in, const int* in_sizes, int n_in,
                              void* d_out, int out_size, void* d_ws, size_t ws_size,
                              hipStream_t stream) {
    const float* ts = (const float*)d_in[0];
    const float* y0 = (const float*)d_in[1];
    const float* W0 = (const float*)d_in[2];
    const float* b0 = (const float*)d_in[3];
    const float* W1 = (const float*)d_in[4];
    const float* b1 = (const float*)d_in[5];
    const float* W2 = (const float*)d_in[6];
    const float* b2 = (const float*)d_in[7];
    const float* W3 = (const float*)d_in[8];
    const float* b3 = (const float*)d_in[9];

    dde_mfma<<<dim3(BATCH / RPB), dim3(NT), 0, stream>>>(
        ts, y0, W0, b0, W1, b1, W2, b2, W3, b3, (float*)d_out);
}